// Round 2
// baseline (1783.159 us; speedup 1.0000x reference)
//
#include <hip/hip_runtime.h>
#include <math.h>

#define N_NODES 50000
#define N_EDGES 600000
#define HID 128
#define N_GRAPHS 64
#define BCAP 32        // bucket capacity; overflow folded into rare path
#define OVF_CAP 4096
#define PCHUNK 8
#define LDSP 136       // padded LDS row stride (bf16) for h tile
#define NB 32          // nodes per fused block
#define AST 132        // accf row stride (f32): 132%32==4 -> 2-way (free) b128 reads

typedef __attribute__((ext_vector_type(8))) short short8;
typedef __attribute__((ext_vector_type(4))) float floatx4;

__device__ __forceinline__ float softplus_f(float v) {
    return fmaxf(v, 0.0f) + __logf(1.0f + __expf(-fabsf(v)));
}
__device__ __forceinline__ unsigned short f2bf(float f) {
    unsigned u = __float_as_uint(f);
    u = (u + 0x7FFFu + ((u >> 16) & 1u)) >> 16;   // RNE; inputs finite
    return (unsigned short)u;
}
__device__ __forceinline__ float bflo(unsigned u) { return __uint_as_float(u << 16); }
__device__ __forceinline__ float bfhi(unsigned u) { return __uint_as_float(u & 0xFFFF0000u); }

// ---- f32 -> bf16 row-major pack (node_attr) ----
__global__ void pack_x(const float* __restrict__ xf, unsigned short* __restrict__ xb, int nelem4) {
    int t = blockIdx.x * 256 + threadIdx.x;
    if (t >= nelem4) return;
    float4 v = *(const float4*)(xf + (size_t)t * 4);
    unsigned o0 = (unsigned)f2bf(v.x) | ((unsigned)f2bf(v.y) << 16);
    unsigned o1 = (unsigned)f2bf(v.z) | ((unsigned)f2bf(v.w) << 16);
    *(uint2*)(xb + (size_t)t * 4) = make_uint2(o0, o1);
}

// ---- bucket build: slot = atomicAdd(cnt[dst]); overflow keeps (e,src,dst) ----
__global__ void build_buckets(const int* __restrict__ ei, int* __restrict__ cnt,
                              int2* __restrict__ bkt, int4* __restrict__ ovf) {
    int e = blockIdx.x * 256 + threadIdx.x;
    if (e >= N_EDGES) return;
    int src = ei[e];
    int dst = ei[N_EDGES + e];
    int slot = atomicAdd(&cnt[dst], 1);
    if (slot < BCAP) {
        bkt[(size_t)dst * BCAP + slot] = make_int2(e, src);
    } else {
        int k = atomicAdd(&cnt[N_NODES], 1);
        if (k < OVF_CAP) ovf[k] = make_int4(e, src, dst, 0);
    }
}

// ---- pack W[n][k] (f32) into MFMA B-frag layout (bf16) ----
__global__ void pack_w(const float* __restrict__ W1, const float* __restrict__ W2,
                       unsigned short* __restrict__ pw) {
    int t = blockIdx.x * 256 + threadIdx.x;
    if (t >= 6 * 32 * 64) return;
    int lane = t & 63;
    int tile = (t >> 6) & 31;
    int mat = t >> 11;                       // 0..5 = layer*2 + which
    int kt = tile >> 3, nt = tile & 7;
    const float* W = (mat & 1) ? W2 : W1;
    W += (size_t)(mat >> 1) * HID * HID;
    int n = nt * 16 + (lane & 15);
    int kbase = kt * 32 + (lane >> 4) * 8;
    short8 v;
    #pragma unroll
    for (int j = 0; j < 8; j++) v[j] = (short)f2bf(W[(size_t)n * HID + kbase + j]);
    *((short8*)(pw + (size_t)t * 8)) = v;
}

// ==== fused layer: agg (flat edge list -> LDS f32 atomics) + 2-GEMM MLP ====
// Shared map (bytes):
//   [0      .. 16896)  accf[NB][AST] f32   (later aliased by hl[2][16][LDSP] u16, 8704 B)
//   [16896  .. 18944)  s_list[1024] u16
//   [18944  .. 19072)  s_cnt[32] int
//   [19072  .. 19208)  s_off[33] int (+pad)
//   [19208  .. 19216)  s_misc[2] int  {tot, ovf_flag}
__global__ void __launch_bounds__(256) layer_fused(
        const unsigned short* __restrict__ xb,
        const float* __restrict__ ef,
        const int* __restrict__ cnt, const int2* __restrict__ bkt,
        const int4* __restrict__ ovf,
        const unsigned short* __restrict__ pw1, const unsigned short* __restrict__ pw2,
        const float* __restrict__ b1, const float* __restrict__ b2,
        void* __restrict__ outp, int final_layer) {
    __shared__ __align__(16) char smem[19216];
    float* accf = (float*)smem;
    unsigned short* s_list = (unsigned short*)(smem + 16896);
    int* s_cnt  = (int*)(smem + 18944);
    int* s_off  = (int*)(smem + 19072);
    int* s_misc = (int*)(smem + 19208);

    int tid = threadIdx.x;
    int n0 = blockIdx.x * NB;

    // zero accumulator; load raw counts
    for (int i = tid; i < NB * AST; i += 256) accf[i] = 0.f;
    if (tid < NB) {
        int n = n0 + tid;
        s_cnt[tid] = (n < N_NODES) ? cnt[n] : 0;
    }
    __syncthreads();
    if (tid == 0) {
        int o = 0, ov = 0;
        #pragma unroll 4
        for (int i = 0; i < NB; i++) {
            int cc = s_cnt[i];
            if (cc > BCAP) { ov = 1; cc = BCAP; }
            s_off[i] = o; o += cc;
        }
        s_off[NB] = o; s_misc[0] = o; s_misc[1] = ov;
    }
    __syncthreads();
    if (tid < NB) {
        int cc = s_cnt[tid]; if (cc > BCAP) cc = BCAP;
        int o = s_off[tid];
        for (int j = 0; j < cc; j++) s_list[o + j] = (unsigned short)((tid << 6) | j);
    }
    __syncthreads();

    int tot = s_misc[0];
    int hw = tid >> 5, l = tid & 31;

    // edge loop: half-wave per edge, depth-2 bucket / depth-1 row prefetch
    if (tot > 0) {
        int2 pA, pB;
        float4 evA; uint2 xvA;
        {
            int ka = (hw < tot) ? hw : 0;
            int va = s_list[ka];
            pA = bkt[(size_t)(n0 + (va >> 6)) * BCAP + (va & 63)];
            int kb = (hw + 8 < tot) ? hw + 8 : 0;
            int vb = s_list[kb];
            pB = bkt[(size_t)(n0 + (vb >> 6)) * BCAP + (vb & 63)];
            evA = *(const float4*)(ef + (size_t)pA.x * HID + l * 4);
            xvA = *(const uint2*)(xb + (size_t)pA.y * HID + l * 4);
        }
        for (int k = hw; k < tot; k += 8) {
            // prefetch next rows (entry k+8) and next-next bucket (entry k+16)
            float4 evN = *(const float4*)(ef + (size_t)pB.x * HID + l * 4);
            uint2  xvN = *(const uint2*)(xb + (size_t)pB.y * HID + l * 4);
            int kc = (k + 16 < tot) ? k + 16 : 0;
            int vc = s_list[kc];
            int2 pN = bkt[(size_t)(n0 + (vc >> 6)) * BCAP + (vc & 63)];
            // compute current (entry k)
            int ln = s_list[k] >> 6;
            float* ac = accf + ln * AST + l * 4;
            atomicAdd(ac + 0, softplus_f(evA.x + bflo(xvA.x)));
            atomicAdd(ac + 1, softplus_f(evA.y + bfhi(xvA.x)));
            atomicAdd(ac + 2, softplus_f(evA.z + bflo(xvA.y)));
            atomicAdd(ac + 3, softplus_f(evA.w + bfhi(xvA.y)));
            pB = pN; evA = evN; xvA = xvN;
        }
    }
    if (s_misc[1]) {        // rare overflow edges
        int kov = cnt[N_NODES]; if (kov > OVF_CAP) kov = OVF_CAP;
        if (hw == 0) {
            for (int i = 0; i < kov; i++) {
                int4 t = ovf[i];
                if (t.z >= n0 && t.z < n0 + NB) {
                    float4 ev = *(const float4*)(ef + (size_t)t.x * HID + l * 4);
                    uint2  xv = *(const uint2*)(xb + (size_t)t.y * HID + l * 4);
                    float* ac = accf + (t.z - n0) * AST + l * 4;
                    atomicAdd(ac + 0, softplus_f(ev.x + bflo(xv.x)));
                    atomicAdd(ac + 1, softplus_f(ev.y + bfhi(xv.x)));
                    atomicAdd(ac + 2, softplus_f(ev.z + bflo(xv.y)));
                    atomicAdd(ac + 3, softplus_f(ev.w + bfhi(xv.y)));
                }
            }
        }
    }
    __syncthreads();

    // ---- MLP phase ----
    int wave = tid >> 6, lane = tid & 63;
    int rt = wave >> 1, ch = wave & 1;
    int m = lane & 15, q = lane >> 4;
    int r0 = n0 + rt * 16;
    int row = r0 + m;
    bool rv = row < N_NODES;
    int lm = rt * 16 + m;

    // build A-frags: af[kt] = bf16( accf[row] + x[row] )
    short8 af[4];
    #pragma unroll
    for (int kt = 0; kt < 4; kt++) {
        const float* ap = accf + (size_t)lm * AST + kt * 32 + q * 8;
        float4 a0 = *(const float4*)(ap);
        float4 a1 = *(const float4*)(ap + 4);
        uint4 xv = rv ? *(const uint4*)(xb + (size_t)row * HID + kt * 32 + q * 8)
                      : make_uint4(0, 0, 0, 0);
        af[kt][0] = (short)f2bf(a0.x + bflo(xv.x));
        af[kt][1] = (short)f2bf(a0.y + bfhi(xv.x));
        af[kt][2] = (short)f2bf(a0.z + bflo(xv.y));
        af[kt][3] = (short)f2bf(a0.w + bfhi(xv.y));
        af[kt][4] = (short)f2bf(a1.x + bflo(xv.z));
        af[kt][5] = (short)f2bf(a1.y + bfhi(xv.z));
        af[kt][6] = (short)f2bf(a1.z + bflo(xv.w));
        af[kt][7] = (short)f2bf(a1.w + bfhi(xv.w));
    }
    __syncthreads();    // all accf reads done -> hl alias region free

    unsigned short* hlp = (unsigned short*)smem;   // hl[32][LDSP] aliased over accf

    floatx4 zero = {0.f, 0.f, 0.f, 0.f};
    floatx4 acc[4];
    #pragma unroll
    for (int t = 0; t < 4; t++) acc[t] = zero;
    const short8* w1 = (const short8*)pw1;
    #pragma unroll
    for (int kt = 0; kt < 4; kt++) {
        const short8* wp = w1 + (size_t)(kt * 8 + ch * 4) * 64 + lane;
        #pragma unroll
        for (int t = 0; t < 4; t++)
            acc[t] = __builtin_amdgcn_mfma_f32_16x16x32_bf16(af[kt], wp[t * 64], acc[t], 0, 0, 0);
    }
    // epilogue 1: h = softplus(acc + b1) -> bf16 -> hl (C-layout -> A-layout)
    #pragma unroll
    for (int t = 0; t < 4; t++) {
        int col = ch * 64 + t * 16 + m;
        float bb = b1[col];
        #pragma unroll
        for (int i = 0; i < 4; i++)
            hlp[(size_t)(rt * 16 + q * 4 + i) * LDSP + col] = f2bf(softplus_f(acc[t][i] + bb));
    }
    __syncthreads();
    #pragma unroll
    for (int t = 0; t < 4; t++) acc[t] = zero;
    const short8* w2 = (const short8*)pw2;
    #pragma unroll
    for (int kt = 0; kt < 4; kt++) {
        short8 hf = *(const short8*)&hlp[(size_t)(rt * 16 + m) * LDSP + kt * 32 + q * 8];
        const short8* wp = w2 + (size_t)(kt * 8 + ch * 4) * 64 + lane;
        #pragma unroll
        for (int t = 0; t < 4; t++)
            acc[t] = __builtin_amdgcn_mfma_f32_16x16x32_bf16(hf, wp[t * 64], acc[t], 0, 0, 0);
    }
    if (final_layer) {
        float* out = (float*)outp;
        #pragma unroll
        for (int t = 0; t < 4; t++) {
            int col = ch * 64 + t * 16 + m;
            float bb = b2[col];
            #pragma unroll
            for (int i = 0; i < 4; i++) {
                int r = r0 + q * 4 + i;
                if (r < N_NODES) out[(size_t)r * HID + col] = acc[t][i] + bb;
            }
        }
    } else {
        __syncthreads();    // all GEMM2 hl reads done before overwrite
        #pragma unroll
        for (int t = 0; t < 4; t++) {
            int col = ch * 64 + t * 16 + m;
            float bb = b2[col];
            #pragma unroll
            for (int i = 0; i < 4; i++)
                hlp[(size_t)(rt * 16 + q * 4 + i) * LDSP + col] = f2bf(softplus_f(acc[t][i] + bb));
        }
        __syncthreads();
        // coalesced copy-out: thread -> (row = tid>>3, 16-col segment)
        unsigned short* outb = (unsigned short*)outp;
        int orow = tid >> 3, cseg = (tid & 7) * 16;
        int gr = n0 + orow;
        if (gr < N_NODES) {
            uint4 v0 = *(const uint4*)&hlp[(size_t)orow * LDSP + cseg];
            uint4 v1 = *(const uint4*)&hlp[(size_t)orow * LDSP + cseg + 8];
            *(uint4*)(outb + (size_t)gr * HID + cseg) = v0;
            *(uint4*)(outb + (size_t)gr * HID + cseg + 8) = v1;
        }
    }
}

// ---- pool: sorted batch -> boundaries -> chunked partials -> reduce ----
__global__ void find_bounds(const int* __restrict__ batch, int* __restrict__ start) {
    int n = blockIdx.x * 256 + threadIdx.x;
    if (n >= N_NODES) return;
    int bn = batch[n];
    int bp = (n == 0) ? -1 : batch[n - 1];
    for (int g = bp + 1; g <= bn; g++) start[g] = n;
    if (n == N_NODES - 1)
        for (int g = bn + 1; g <= N_GRAPHS; g++) start[g] = N_NODES;
}

__global__ void pool_partial(const float* __restrict__ nf, const int* __restrict__ start,
                             float* __restrict__ part) {
    int g = blockIdx.x >> 3, c = blockIdx.x & (PCHUNK - 1);
    int j = threadIdx.x;
    int s = start[g], e = start[g + 1];
    int len = e - s;
    int b0 = s + (len * c) / PCHUNK;
    int b1 = s + (len * (c + 1)) / PCHUNK;
    float acc = 0.f;
    for (int n = b0; n < b1; n++) acc += nf[(size_t)n * HID + j];
    part[(size_t)blockIdx.x * HID + j] = acc;
}

__global__ void pool_final(const float* __restrict__ part, float* __restrict__ gout) {
    int g = blockIdx.x, j = threadIdx.x;
    float acc = 0.f;
    #pragma unroll
    for (int c = 0; c < PCHUNK; c++) acc += part[(size_t)(g * PCHUNK + c) * HID + j];
    gout[(size_t)g * HID + j] = acc;
}

extern "C" void kernel_launch(void* const* d_in, const int* in_sizes, int n_in,
                              void* d_out, int out_size, void* d_ws, size_t ws_size,
                              hipStream_t stream) {
    const float* node_attr = (const float*)d_in[0];
    const float* edge_attr = (const float*)d_in[1];
    const int*   ei        = (const int*)d_in[2];
    const int*   batch     = (const int*)d_in[3];
    const float* W1        = (const float*)d_in[4];
    const float* B1        = (const float*)d_in[5];
    const float* W2        = (const float*)d_in[6];
    const float* B2        = (const float*)d_in[7];

    float* gout    = (float*)d_out;                    // [64,128]
    float* nodeout = (float*)d_out + N_GRAPHS * HID;   // [50000,128]

    const size_t NH = (size_t)N_NODES * HID;
    unsigned short* nab  = (unsigned short*)d_ws;      // bf16 node_attr
    unsigned short* buf0 = nab + NH;                   // bf16 x after layer 0
    unsigned short* buf1 = buf0 + NH;                  // bf16 x after layer 1
    int*   cnt = (int*)(buf1 + NH);                    // 50001 (+pad)
    int4*  ovf = (int4*)(cnt + 50004);                 // OVF_CAP (16B aligned)
    int2*  bkt = (int2*)(ovf + OVF_CAP);               // 50000*BCAP
    unsigned short* pw = (unsigned short*)(bkt + (size_t)N_NODES * BCAP);  // 6*16384
    int*   startb = (int*)(pw + 6 * 16384);            // 65 (+pad)
    float* part = (float*)(startb + 68);               // 64*PCHUNK*128

    hipMemsetAsync(cnt, 0, (size_t)50001 * sizeof(int), stream);
    build_buckets<<<(N_EDGES + 255) / 256, 256, 0, stream>>>(ei, cnt, bkt, ovf);
    pack_w<<<(6 * 32 * 64 + 255) / 256, 256, 0, stream>>>(W1, W2, pw);
    pack_x<<<((int)(NH / 4) + 255) / 256, 256, 0, stream>>>(node_attr, nab, (int)(NH / 4));
    find_bounds<<<(N_NODES + 255) / 256, 256, 0, stream>>>(batch, startb);

    const int blocks = (N_NODES + NB - 1) / NB;

    const unsigned short* xin[3] = { nab, buf0, buf1 };
    void* xout[3] = { (void*)buf0, (void*)buf1, (void*)nodeout };
    for (int i = 0; i < 3; i++) {
        layer_fused<<<blocks, 256, 0, stream>>>(xin[i], edge_attr, cnt, bkt, ovf,
                pw + (size_t)(i * 2) * 16384, pw + (size_t)(i * 2 + 1) * 16384,
                B1 + (size_t)i * HID, B2 + (size_t)i * HID, xout[i], (i == 2) ? 1 : 0);
    }
    pool_partial<<<N_GRAPHS * PCHUNK, HID, 0, stream>>>(nodeout, startb, part);
    pool_final<<<N_GRAPHS, HID, 0, stream>>>(part, gout);
}

// Round 3
// 1186.566 us; speedup vs baseline: 1.5028x; 1.5028x over previous
//
#include <hip/hip_runtime.h>
#include <math.h>

#define N_NODES 50000
#define N_EDGES 600000
#define HID 128
#define N_GRAPHS 64
#define BCAP 32        // bucket capacity; overflow folded into agg rare path
#define OVF_CAP 4096
#define PCHUNK 8
#define LDSP 136       // padded LDS row stride (bf16): 272B = 17*16B -> bank-rotates A-frag reads

typedef __attribute__((ext_vector_type(8))) short short8;
typedef __attribute__((ext_vector_type(4))) float floatx4;

__device__ __forceinline__ float softplus_f(float v) {
    return fmaxf(v, 0.0f) + __logf(1.0f + __expf(-fabsf(v)));
}
__device__ __forceinline__ unsigned short f2bf(float f) {
    unsigned u = __float_as_uint(f);
    u = (u + 0x7FFFu + ((u >> 16) & 1u)) >> 16;   // RNE; inputs finite
    return (unsigned short)u;
}
__device__ __forceinline__ float bflo(unsigned u) { return __uint_as_float(u << 16); }
__device__ __forceinline__ float bfhi(unsigned u) { return __uint_as_float(u & 0xFFFF0000u); }
__device__ __forceinline__ uint2 bfpack4(float4 v) {
    uint2 o;
    o.x = (unsigned)f2bf(v.x) | ((unsigned)f2bf(v.y) << 16);
    o.y = (unsigned)f2bf(v.z) | ((unsigned)f2bf(v.w) << 16);
    return o;
}

// ---- f32 -> bf16 row-major pack (node_attr) ----
__global__ void pack_x(const float* __restrict__ xf, unsigned short* __restrict__ xb, int nelem4) {
    int t = blockIdx.x * 256 + threadIdx.x;
    if (t >= nelem4) return;
    float4 v = *(const float4*)(xf + (size_t)t * 4);
    unsigned o0 = (unsigned)f2bf(v.x) | ((unsigned)f2bf(v.y) << 16);
    unsigned o1 = (unsigned)f2bf(v.z) | ((unsigned)f2bf(v.w) << 16);
    *(uint2*)(xb + (size_t)t * 4) = make_uint2(o0, o1);
}

// ---- bucket build: slot = atomicAdd(cnt[dst]); overflow keeps (e,src,dst) ----
__global__ void build_buckets(const int* __restrict__ ei, int* __restrict__ cnt,
                              int2* __restrict__ bkt, int4* __restrict__ ovf) {
    int e = blockIdx.x * 256 + threadIdx.x;
    if (e >= N_EDGES) return;
    int src = ei[e];
    int dst = ei[N_EDGES + e];
    int slot = atomicAdd(&cnt[dst], 1);
    if (slot < BCAP) {
        bkt[(size_t)dst * BCAP + slot] = make_int2(e, src);
    } else {
        int k = atomicAdd(&cnt[N_NODES], 1);
        if (k < OVF_CAP) ovf[k] = make_int4(e, src, dst, 0);
    }
}

// ---- agg pass 0: wave/node, half-wave/edge (round-0 structure, verbatim) ----
// Extra vs round-0: each gathered f32 edge row is ALSO stored bf16 into the
// dst-ordered dense CSR array ebs at off[n]+slot (off allocated via one
// atomicAdd per node). Passes 1-2 then stream ebs sequentially.
__global__ void __launch_bounds__(256) agg_pass0(const unsigned short* __restrict__ xb,
        const float* __restrict__ edge_attr, const int* __restrict__ cnt,
        const int2* __restrict__ bkt, const int4* __restrict__ ovf,
        unsigned short* __restrict__ outb,
        unsigned short* __restrict__ ebs, int* __restrict__ off, int* __restrict__ galloc) {
    int wave = blockIdx.x * 4 + (threadIdx.x >> 6);
    int lane = threadIdx.x & 63;
    int n = __builtin_amdgcn_readfirstlane(wave);
    if (n >= N_NODES) return;
    int h = lane >> 5;          // which edge of a pair this half-wave handles
    int l = lane & 31;          // float4 index in the 128-feat row
    int ctot = cnt[n];
    int c = ctot < BCAP ? ctot : BCAP;
    int pos0 = 0;
    if (lane == 0 && c > 0) {
        pos0 = atomicAdd(galloc, c);
        off[n] = pos0;
    }
    pos0 = __shfl(pos0, 0);
    const int2* bk = bkt + (size_t)n * BCAP;
    float4 acc = make_float4(0.f, 0.f, 0.f, 0.f);
    int s = 0;
    for (; s + 4 <= c; s += 4) {
        int2 pA = bk[s + h];
        int2 pB = bk[s + 2 + h];
        float4 eA = *(const float4*)(edge_attr + (size_t)pA.x * HID + l * 4);
        uint2  xA = *(const uint2*)(xb + (size_t)pA.y * HID + l * 4);
        float4 eB = *(const float4*)(edge_attr + (size_t)pB.x * HID + l * 4);
        uint2  xB = *(const uint2*)(xb + (size_t)pB.y * HID + l * 4);
        *(uint2*)(ebs + (size_t)(pos0 + s + h) * HID + l * 4) = bfpack4(eA);
        *(uint2*)(ebs + (size_t)(pos0 + s + 2 + h) * HID + l * 4) = bfpack4(eB);
        acc.x += softplus_f(eA.x + bflo(xA.x)) + softplus_f(eB.x + bflo(xB.x));
        acc.y += softplus_f(eA.y + bfhi(xA.x)) + softplus_f(eB.y + bfhi(xB.x));
        acc.z += softplus_f(eA.z + bflo(xA.y)) + softplus_f(eB.z + bflo(xB.y));
        acc.w += softplus_f(eA.w + bfhi(xA.y)) + softplus_f(eB.w + bfhi(xB.y));
    }
    if (s + 2 <= c) {
        int2 p = bk[s + h];
        float4 ev = *(const float4*)(edge_attr + (size_t)p.x * HID + l * 4);
        uint2  xv = *(const uint2*)(xb + (size_t)p.y * HID + l * 4);
        *(uint2*)(ebs + (size_t)(pos0 + s + h) * HID + l * 4) = bfpack4(ev);
        acc.x += softplus_f(ev.x + bflo(xv.x));
        acc.y += softplus_f(ev.y + bfhi(xv.x));
        acc.z += softplus_f(ev.z + bflo(xv.y));
        acc.w += softplus_f(ev.w + bfhi(xv.y));
        s += 2;
    }
    if (s < c && h == 0) {
        int2 p = bk[s];
        float4 ev = *(const float4*)(edge_attr + (size_t)p.x * HID + l * 4);
        uint2  xv = *(const uint2*)(xb + (size_t)p.y * HID + l * 4);
        *(uint2*)(ebs + (size_t)(pos0 + s) * HID + l * 4) = bfpack4(ev);
        acc.x += softplus_f(ev.x + bflo(xv.x));
        acc.y += softplus_f(ev.y + bfhi(xv.x));
        acc.z += softplus_f(ev.z + bflo(xv.y));
        acc.w += softplus_f(ev.w + bfhi(xv.y));
    }
    if (ctot > BCAP) {          // rare: scan overflow list for this dst
        int k = cnt[N_NODES]; if (k > OVF_CAP) k = OVF_CAP;
        for (int i = 0; i < k; i++) {
            int4 t = ovf[i];
            if (t.z == n && h == 0) {
                float4 ev = *(const float4*)(edge_attr + (size_t)t.x * HID + l * 4);
                uint2  xv = *(const uint2*)(xb + (size_t)t.y * HID + l * 4);
                acc.x += softplus_f(ev.x + bflo(xv.x));
                acc.y += softplus_f(ev.y + bfhi(xv.x));
                acc.z += softplus_f(ev.z + bflo(xv.y));
                acc.w += softplus_f(ev.w + bfhi(xv.y));
            }
        }
    }
    acc.x += __shfl(acc.x, l + 32);
    acc.y += __shfl(acc.y, l + 32);
    acc.z += __shfl(acc.z, l + 32);
    acc.w += __shfl(acc.w, l + 32);
    if (h == 0) {
        uint2 xn = *(const uint2*)(xb + (size_t)n * HID + l * 4);
        acc.x += bflo(xn.x); acc.y += bfhi(xn.x);
        acc.z += bflo(xn.y); acc.w += bfhi(xn.y);
        unsigned o0 = (unsigned)f2bf(acc.x) | ((unsigned)f2bf(acc.y) << 16);
        unsigned o1 = (unsigned)f2bf(acc.z) | ((unsigned)f2bf(acc.w) << 16);
        *(uint2*)(outb + (size_t)n * HID + l * 4) = make_uint2(o0, o1);
    }
}

// ---- agg passes 1-2: same structure; edge rows stream SEQUENTIALLY from ebs ----
__global__ void __launch_bounds__(256) agg_pass12(const unsigned short* __restrict__ xb,
        const float* __restrict__ edge_attr, const int* __restrict__ cnt,
        const int2* __restrict__ bkt, const int4* __restrict__ ovf,
        unsigned short* __restrict__ outb,
        const unsigned short* __restrict__ ebs, const int* __restrict__ off) {
    int wave = blockIdx.x * 4 + (threadIdx.x >> 6);
    int lane = threadIdx.x & 63;
    int n = __builtin_amdgcn_readfirstlane(wave);
    if (n >= N_NODES) return;
    int h = lane >> 5;
    int l = lane & 31;
    int ctot = cnt[n];
    int c = ctot < BCAP ? ctot : BCAP;
    int p0 = (c > 0) ? off[n] : 0;
    const int2* bk = bkt + (size_t)n * BCAP;
    const unsigned short* er = ebs + (size_t)p0 * HID;
    float4 acc = make_float4(0.f, 0.f, 0.f, 0.f);
    int s = 0;
    for (; s + 4 <= c; s += 4) {
        int2 pA = bk[s + h];
        int2 pB = bk[s + 2 + h];
        uint2 eA = *(const uint2*)(er + (size_t)(s + h) * HID + l * 4);
        uint2 xA = *(const uint2*)(xb + (size_t)pA.y * HID + l * 4);
        uint2 eB = *(const uint2*)(er + (size_t)(s + 2 + h) * HID + l * 4);
        uint2 xB = *(const uint2*)(xb + (size_t)pB.y * HID + l * 4);
        acc.x += softplus_f(bflo(eA.x) + bflo(xA.x)) + softplus_f(bflo(eB.x) + bflo(xB.x));
        acc.y += softplus_f(bfhi(eA.x) + bfhi(xA.x)) + softplus_f(bfhi(eB.x) + bfhi(xB.x));
        acc.z += softplus_f(bflo(eA.y) + bflo(xA.y)) + softplus_f(bflo(eB.y) + bflo(xB.y));
        acc.w += softplus_f(bfhi(eA.y) + bfhi(xA.y)) + softplus_f(bfhi(eB.y) + bfhi(xB.y));
    }
    if (s + 2 <= c) {
        int2 p = bk[s + h];
        uint2 ev = *(const uint2*)(er + (size_t)(s + h) * HID + l * 4);
        uint2 xv = *(const uint2*)(xb + (size_t)p.y * HID + l * 4);
        acc.x += softplus_f(bflo(ev.x) + bflo(xv.x));
        acc.y += softplus_f(bfhi(ev.x) + bfhi(xv.x));
        acc.z += softplus_f(bflo(ev.y) + bflo(xv.y));
        acc.w += softplus_f(bfhi(ev.y) + bfhi(xv.y));
        s += 2;
    }
    if (s < c && h == 0) {
        int2 p = bk[s];
        uint2 ev = *(const uint2*)(er + (size_t)s * HID + l * 4);
        uint2 xv = *(const uint2*)(xb + (size_t)p.y * HID + l * 4);
        acc.x += softplus_f(bflo(ev.x) + bflo(xv.x));
        acc.y += softplus_f(bfhi(ev.x) + bfhi(xv.x));
        acc.z += softplus_f(bflo(ev.y) + bflo(xv.y));
        acc.w += softplus_f(bfhi(ev.y) + bfhi(xv.y));
    }
    if (ctot > BCAP) {          // rare: overflow edges re-read f32
        int k = cnt[N_NODES]; if (k > OVF_CAP) k = OVF_CAP;
        for (int i = 0; i < k; i++) {
            int4 t = ovf[i];
            if (t.z == n && h == 0) {
                float4 ev = *(const float4*)(edge_attr + (size_t)t.x * HID + l * 4);
                uint2  xv = *(const uint2*)(xb + (size_t)t.y * HID + l * 4);
                acc.x += softplus_f(ev.x + bflo(xv.x));
                acc.y += softplus_f(ev.y + bfhi(xv.x));
                acc.z += softplus_f(ev.z + bflo(xv.y));
                acc.w += softplus_f(ev.w + bfhi(xv.y));
            }
        }
    }
    acc.x += __shfl(acc.x, l + 32);
    acc.y += __shfl(acc.y, l + 32);
    acc.z += __shfl(acc.z, l + 32);
    acc.w += __shfl(acc.w, l + 32);
    if (h == 0) {
        uint2 xn = *(const uint2*)(xb + (size_t)n * HID + l * 4);
        acc.x += bflo(xn.x); acc.y += bfhi(xn.x);
        acc.z += bflo(xn.y); acc.w += bfhi(xn.y);
        unsigned o0 = (unsigned)f2bf(acc.x) | ((unsigned)f2bf(acc.y) << 16);
        unsigned o1 = (unsigned)f2bf(acc.z) | ((unsigned)f2bf(acc.w) << 16);
        *(uint2*)(outb + (size_t)n * HID + l * 4) = make_uint2(o0, o1);
    }
}

// ---- pack W[n][k] (f32) into MFMA B-frag layout (bf16) ----
__global__ void pack_w(const float* __restrict__ W1, const float* __restrict__ W2,
                       unsigned short* __restrict__ pw) {
    int t = blockIdx.x * 256 + threadIdx.x;
    if (t >= 6 * 32 * 64) return;
    int lane = t & 63;
    int tile = (t >> 6) & 31;
    int mat = t >> 11;                       // 0..5 = layer*2 + which
    int kt = tile >> 3, nt = tile & 7;
    const float* W = (mat & 1) ? W2 : W1;
    W += (size_t)(mat >> 1) * HID * HID;
    int n = nt * 16 + (lane & 15);
    int kbase = kt * 32 + (lane >> 4) * 8;
    short8 v;
    #pragma unroll
    for (int j = 0; j < 8; j++) v[j] = (short)f2bf(W[(size_t)n * HID + kbase + j]);
    *((short8*)(pw + (size_t)t * 8)) = v;
}

// ---- fused MLP: out = [softplus]( softplus(A@W1^T+b1) @ W2^T + b2 ) ----
// block = 4 waves: 2 row-tiles x 2 col-halves; h round-trips via LDS (bf16).
__global__ void __launch_bounds__(256) mlp_fused(const unsigned short* __restrict__ A,
        const unsigned short* __restrict__ pw1, const unsigned short* __restrict__ pw2,
        const float* __restrict__ b1, const float* __restrict__ b2,
        void* __restrict__ outp, int final_layer) {
    __shared__ __align__(16) unsigned short hl[2][16][LDSP];
    int wave = threadIdx.x >> 6, lane = threadIdx.x & 63;
    int rt = wave >> 1, ch = wave & 1;
    int m = lane & 15, q = lane >> 4;
    int r0 = blockIdx.x * 32 + rt * 16;
    int row = r0 + m;
    bool rv = row < N_NODES;
    short8 zf = {0, 0, 0, 0, 0, 0, 0, 0};
    floatx4 zero = {0.f, 0.f, 0.f, 0.f};
    floatx4 acc[4];
    #pragma unroll
    for (int t = 0; t < 4; t++) acc[t] = zero;
    const short8* ar = (const short8*)(A + (size_t)row * HID + q * 8);
    const short8* w1 = (const short8*)pw1;
    #pragma unroll
    for (int kt = 0; kt < 4; kt++) {
        short8 af = rv ? ar[kt * 4] : zf;   // A[row][kt*32+q*8 ..+8], direct bf16
        const short8* wp = w1 + (size_t)(kt * 8 + ch * 4) * 64 + lane;
        #pragma unroll
        for (int t = 0; t < 4; t++)
            acc[t] = __builtin_amdgcn_mfma_f32_16x16x32_bf16(af, wp[t * 64], acc[t], 0, 0, 0);
    }
    // epilogue 1: h = softplus(acc + b1) -> bf16 -> LDS (C-layout -> A-layout)
    #pragma unroll
    for (int t = 0; t < 4; t++) {
        int col = ch * 64 + t * 16 + m;
        float bb = b1[col];
        #pragma unroll
        for (int i = 0; i < 4; i++)
            hl[rt][q * 4 + i][col] = f2bf(softplus_f(acc[t][i] + bb));
    }
    __syncthreads();
    #pragma unroll
    for (int t = 0; t < 4; t++) acc[t] = zero;
    const short8* w2 = (const short8*)pw2;
    #pragma unroll
    for (int kt = 0; kt < 4; kt++) {
        short8 af = *(const short8*)&hl[rt][m][kt * 32 + q * 8];
        const short8* wp = w2 + (size_t)(kt * 8 + ch * 4) * 64 + lane;
        #pragma unroll
        for (int t = 0; t < 4; t++)
            acc[t] = __builtin_amdgcn_mfma_f32_16x16x32_bf16(af, wp[t * 64], acc[t], 0, 0, 0);
    }
    if (final_layer) {
        float* out = (float*)outp;
        #pragma unroll
        for (int t = 0; t < 4; t++) {
            int col = ch * 64 + t * 16 + m;
            float bb = b2[col];
            #pragma unroll
            for (int i = 0; i < 4; i++) {
                int r = r0 + q * 4 + i;
                if (r < N_NODES) out[(size_t)r * HID + col] = acc[t][i] + bb;
            }
        }
    } else {
        __syncthreads();    // all GEMM2 LDS reads done before overwrite
        #pragma unroll
        for (int t = 0; t < 4; t++) {
            int col = ch * 64 + t * 16 + m;
            float bb = b2[col];
            #pragma unroll
            for (int i = 0; i < 4; i++)
                hl[rt][q * 4 + i][col] = f2bf(softplus_f(acc[t][i] + bb));
        }
        __syncthreads();
        // coalesced copy-out: thread -> (row = tid>>3, 16-col segment)
        unsigned short* outb = (unsigned short*)outp;
        int tid = threadIdx.x;
        int orow = tid >> 3, cseg = (tid & 7) * 16;
        int gr = blockIdx.x * 32 + orow;
        if (gr < N_NODES) {
            uint4 v0 = *(const uint4*)&hl[orow >> 4][orow & 15][cseg];
            uint4 v1 = *(const uint4*)&hl[orow >> 4][orow & 15][cseg + 8];
            *(uint4*)(outb + (size_t)gr * HID + cseg) = v0;
            *(uint4*)(outb + (size_t)gr * HID + cseg + 8) = v1;
        }
    }
}

// ---- pool: sorted batch -> boundaries -> chunked partials -> reduce ----
__global__ void find_bounds(const int* __restrict__ batch, int* __restrict__ start) {
    int n = blockIdx.x * 256 + threadIdx.x;
    if (n >= N_NODES) return;
    int bn = batch[n];
    int bp = (n == 0) ? -1 : batch[n - 1];
    for (int g = bp + 1; g <= bn; g++) start[g] = n;
    if (n == N_NODES - 1)
        for (int g = bn + 1; g <= N_GRAPHS; g++) start[g] = N_NODES;
}

__global__ void pool_partial(const float* __restrict__ nf, const int* __restrict__ start,
                             float* __restrict__ part) {
    int g = blockIdx.x >> 3, c = blockIdx.x & (PCHUNK - 1);
    int j = threadIdx.x;
    int s = start[g], e = start[g + 1];
    int len = e - s;
    int b0 = s + (len * c) / PCHUNK;
    int b1 = s + (len * (c + 1)) / PCHUNK;
    float acc = 0.f;
    for (int n = b0; n < b1; n++) acc += nf[(size_t)n * HID + j];
    part[(size_t)blockIdx.x * HID + j] = acc;
}

__global__ void pool_final(const float* __restrict__ part, float* __restrict__ gout) {
    int g = blockIdx.x, j = threadIdx.x;
    float acc = 0.f;
    #pragma unroll
    for (int c = 0; c < PCHUNK; c++) acc += part[(size_t)(g * PCHUNK + c) * HID + j];
    gout[(size_t)g * HID + j] = acc;
}

extern "C" void kernel_launch(void* const* d_in, const int* in_sizes, int n_in,
                              void* d_out, int out_size, void* d_ws, size_t ws_size,
                              hipStream_t stream) {
    const float* node_attr = (const float*)d_in[0];
    const float* edge_attr = (const float*)d_in[1];
    const int*   ei        = (const int*)d_in[2];
    const int*   batch     = (const int*)d_in[3];
    const float* W1        = (const float*)d_in[4];
    const float* B1        = (const float*)d_in[5];
    const float* W2        = (const float*)d_in[6];
    const float* B2        = (const float*)d_in[7];

    float* gout    = (float*)d_out;                    // [64,128]
    float* nodeout = (float*)d_out + N_GRAPHS * HID;   // [50000,128]

    const size_t NH = (size_t)N_NODES * HID;
    unsigned short* nab  = (unsigned short*)d_ws;      // bf16 node_attr
    unsigned short* bufA = nab + NH;                   // bf16 agg out (MLP A)
    unsigned short* bufB = bufA + NH;                  // bf16 x between layers
    int*   cnt = (int*)(bufB + NH);                    // [0..49999]=deg, [50000]=ovf, [50001]=galloc
    int4*  ovf = (int4*)(cnt + 50008);                 // OVF_CAP (16B aligned)
    int2*  bkt = (int2*)(ovf + OVF_CAP);               // 50000*BCAP
    unsigned short* pw = (unsigned short*)(bkt + (size_t)N_NODES * BCAP);  // 6*16384
    int*   startb = (int*)(pw + 6 * 16384);            // 65 (+pad)
    float* part = (float*)(startb + 68);               // 64*PCHUNK*128
    int*   off = (int*)(part + (size_t)N_GRAPHS * PCHUNK * HID);  // CSR base per node
    unsigned short* ebs = (unsigned short*)(off + 50000);  // bf16 dst-ordered edge rows

    hipMemsetAsync(cnt, 0, (size_t)50002 * sizeof(int), stream);
    build_buckets<<<(N_EDGES + 255) / 256, 256, 0, stream>>>(ei, cnt, bkt, ovf);
    pack_w<<<(6 * 32 * 64 + 255) / 256, 256, 0, stream>>>(W1, W2, pw);
    pack_x<<<((int)(NH / 4) + 255) / 256, 256, 0, stream>>>(node_attr, nab, (int)(NH / 4));
    find_bounds<<<(N_NODES + 255) / 256, 256, 0, stream>>>(batch, startb);

    const int agg_blocks = (N_NODES + 3) / 4;
    const int mlp_blocks = (N_NODES + 31) / 32;

    const unsigned short* xcur = nab;
    for (int i = 0; i < 3; i++) {
        if (i == 0)
            agg_pass0<<<agg_blocks, 256, 0, stream>>>(xcur, edge_attr, cnt, bkt, ovf,
                    bufA, ebs, off, cnt + 50001);
        else
            agg_pass12<<<agg_blocks, 256, 0, stream>>>(xcur, edge_attr, cnt, bkt, ovf,
                    bufA, ebs, off);
        void* outp = (i == 2) ? (void*)nodeout : (void*)bufB;
        mlp_fused<<<mlp_blocks, 256, 0, stream>>>(bufA,
                pw + (size_t)(i * 2) * 16384, pw + (size_t)(i * 2 + 1) * 16384,
                B1 + (size_t)i * HID, B2 + (size_t)i * HID, outp, (i == 2) ? 1 : 0);
        xcur = bufB;
    }
    pool_partial<<<N_GRAPHS * PCHUNK, HID, 0, stream>>>(nodeout, startb, part);
    pool_final<<<N_GRAPHS, HID, 0, stream>>>(part, gout);
}

// Round 4
// 866.531 us; speedup vs baseline: 2.0578x; 1.3693x over previous
//
#include <hip/hip_runtime.h>
#include <math.h>

#define N_NODES 50000
#define N_EDGES 600000
#define HID 128
#define N_GRAPHS 64
#define BCAP 32        // bucket capacity; overflow folded into agg rare path
#define OVF_CAP 4096
#define PCHUNK 8
#define LDSP 136       // padded LDS row stride (bf16): 272B = 17*16B -> bank-rotates A-frag reads

typedef __attribute__((ext_vector_type(8))) short short8;
typedef __attribute__((ext_vector_type(4))) float floatx4;

__device__ __forceinline__ float softplus_f(float v) {
    return fmaxf(v, 0.0f) + __logf(1.0f + __expf(-fabsf(v)));
}
__device__ __forceinline__ unsigned short f2bf(float f) {
    unsigned u = __float_as_uint(f);
    u = (u + 0x7FFFu + ((u >> 16) & 1u)) >> 16;   // RNE; inputs finite
    return (unsigned short)u;
}
__device__ __forceinline__ float bflo(unsigned u) { return __uint_as_float(u << 16); }
__device__ __forceinline__ float bfhi(unsigned u) { return __uint_as_float(u & 0xFFFF0000u); }
__device__ __forceinline__ uint2 bfpack4(float4 v) {
    uint2 o;
    o.x = (unsigned)f2bf(v.x) | ((unsigned)f2bf(v.y) << 16);
    o.y = (unsigned)f2bf(v.z) | ((unsigned)f2bf(v.w) << 16);
    return o;
}

// ---- f32 -> bf16 row-major pack (node_attr) ----
__global__ void pack_x(const float* __restrict__ xf, unsigned short* __restrict__ xb, int nelem4) {
    int t = blockIdx.x * 256 + threadIdx.x;
    if (t >= nelem4) return;
    float4 v = *(const float4*)(xf + (size_t)t * 4);
    unsigned o0 = (unsigned)f2bf(v.x) | ((unsigned)f2bf(v.y) << 16);
    unsigned o1 = (unsigned)f2bf(v.z) | ((unsigned)f2bf(v.w) << 16);
    *(uint2*)(xb + (size_t)t * 4) = make_uint2(o0, o1);
}

// ---- bucket build: slot = atomicAdd(cnt[dst]); records (dst,slot) per edge ----
__global__ void build_buckets2(const int* __restrict__ ei, int* __restrict__ cnt,
                               int2* __restrict__ sed, int4* __restrict__ ovf) {
    int e = blockIdx.x * 256 + threadIdx.x;
    if (e >= N_EDGES) return;
    int src = ei[e];
    int dst = ei[N_EDGES + e];
    int slot = atomicAdd(&cnt[dst], 1);
    if (slot < BCAP) {
        sed[e] = make_int2(dst, slot);
    } else {
        sed[e] = make_int2(-1, 0);
        int k = atomicAdd(&cnt[N_NODES], 1);
        if (k < OVF_CAP) ovf[k] = make_int4(e, src, dst, 0);
    }
}

// ---- exclusive scan of min(cnt,BCAP) -> off[] ; one block, LDS Hillis-Steele ----
__global__ void __launch_bounds__(1024) scan_off(const int* __restrict__ cnt,
                                                 int* __restrict__ off) {
    __shared__ int ls[1024];
    int t = threadIdx.x;
    const int PER = (N_NODES + 1023) / 1024;   // 49
    int base = t * PER;
    int sum = 0;
    for (int i = 0; i < PER; i++) {
        int n = base + i;
        if (n < N_NODES) { int c = cnt[n]; if (c > BCAP) c = BCAP; sum += c; }
    }
    ls[t] = sum;
    __syncthreads();
    for (int d = 1; d < 1024; d <<= 1) {
        int v = (t >= d) ? ls[t - d] : 0;
        __syncthreads();
        ls[t] += v;
        __syncthreads();
    }
    int run = (t > 0) ? ls[t - 1] : 0;
    for (int i = 0; i < PER; i++) {
        int n = base + i;
        if (n < N_NODES) {
            off[n] = run;
            int c = cnt[n]; if (c > BCAP) c = BCAP;
            run += c;
        }
    }
}

// ---- permute: sequential f32 edge read -> bf16 CSR write at off[dst]+slot ----
// Pays the random-access price ONCE, on the write side; all agg passes then stream.
__global__ void __launch_bounds__(256) permute_e(const float* __restrict__ ef,
        const int2* __restrict__ sed, const int* __restrict__ ei,
        const int* __restrict__ off, unsigned short* __restrict__ ebs,
        int* __restrict__ srcs) {
    int e = blockIdx.x * 8 + (threadIdx.x >> 5);
    if (e >= N_EDGES) return;
    int l = threadIdx.x & 31;
    int2 ds = sed[e];
    if (ds.x < 0) return;               // overflow edge: agg reads f32 directly
    int pos = off[ds.x] + ds.y;
    if (l == 0) srcs[pos] = ei[e];
    float4 v = *(const float4*)(ef + (size_t)e * HID + l * 4);
    *(uint2*)(ebs + (size_t)pos * HID + l * 4) = bfpack4(v);
}

// ---- agg (all 3 passes): wave/node, half-wave/edge; edge rows stream from CSR ----
// outb[n] = bf16( x[n] + sum_e softplus(edge_attr[e] + x[src_e]) )
__global__ void __launch_bounds__(256) agg_seq(const unsigned short* __restrict__ xb,
        const float* __restrict__ edge_attr, const int* __restrict__ cnt,
        const int* __restrict__ srcs, const int4* __restrict__ ovf,
        unsigned short* __restrict__ outb,
        const unsigned short* __restrict__ ebs, const int* __restrict__ off) {
    int wave = blockIdx.x * 4 + (threadIdx.x >> 6);
    int lane = threadIdx.x & 63;
    int n = __builtin_amdgcn_readfirstlane(wave);
    if (n >= N_NODES) return;
    int h = lane >> 5;          // which edge of a pair this half-wave handles
    int l = lane & 31;          // uint2 index in the 128-feat bf16 row
    int ctot = cnt[n];
    int c = ctot < BCAP ? ctot : BCAP;
    int p0 = (c > 0) ? off[n] : 0;
    const int* sr = srcs + p0;
    const unsigned short* er = ebs + (size_t)p0 * HID;
    float4 acc = make_float4(0.f, 0.f, 0.f, 0.f);
    int s = 0;
    for (; s + 4 <= c; s += 4) {
        int srcA = sr[s + h];
        int srcB = sr[s + 2 + h];
        uint2 eA = *(const uint2*)(er + (size_t)(s + h) * HID + l * 4);
        uint2 xA = *(const uint2*)(xb + (size_t)srcA * HID + l * 4);
        uint2 eB = *(const uint2*)(er + (size_t)(s + 2 + h) * HID + l * 4);
        uint2 xB = *(const uint2*)(xb + (size_t)srcB * HID + l * 4);
        acc.x += softplus_f(bflo(eA.x) + bflo(xA.x)) + softplus_f(bflo(eB.x) + bflo(xB.x));
        acc.y += softplus_f(bfhi(eA.x) + bfhi(xA.x)) + softplus_f(bfhi(eB.x) + bfhi(xB.x));
        acc.z += softplus_f(bflo(eA.y) + bflo(xA.y)) + softplus_f(bflo(eB.y) + bflo(xB.y));
        acc.w += softplus_f(bfhi(eA.y) + bfhi(xA.y)) + softplus_f(bfhi(eB.y) + bfhi(xB.y));
    }
    if (s + 2 <= c) {
        int sc = sr[s + h];
        uint2 ev = *(const uint2*)(er + (size_t)(s + h) * HID + l * 4);
        uint2 xv = *(const uint2*)(xb + (size_t)sc * HID + l * 4);
        acc.x += softplus_f(bflo(ev.x) + bflo(xv.x));
        acc.y += softplus_f(bfhi(ev.x) + bfhi(xv.x));
        acc.z += softplus_f(bflo(ev.y) + bflo(xv.y));
        acc.w += softplus_f(bfhi(ev.y) + bfhi(xv.y));
        s += 2;
    }
    if (s < c && h == 0) {
        int sc = sr[s];
        uint2 ev = *(const uint2*)(er + (size_t)s * HID + l * 4);
        uint2 xv = *(const uint2*)(xb + (size_t)sc * HID + l * 4);
        acc.x += softplus_f(bflo(ev.x) + bflo(xv.x));
        acc.y += softplus_f(bfhi(ev.x) + bfhi(xv.x));
        acc.z += softplus_f(bflo(ev.y) + bflo(xv.y));
        acc.w += softplus_f(bfhi(ev.y) + bfhi(xv.y));
    }
    if (ctot > BCAP) {          // rare: scan overflow list for this dst (f32 rows)
        int k = cnt[N_NODES]; if (k > OVF_CAP) k = OVF_CAP;
        for (int i = 0; i < k; i++) {
            int4 t = ovf[i];
            if (t.z == n && h == 0) {
                float4 ev = *(const float4*)(edge_attr + (size_t)t.x * HID + l * 4);
                uint2  xv = *(const uint2*)(xb + (size_t)t.y * HID + l * 4);
                acc.x += softplus_f(ev.x + bflo(xv.x));
                acc.y += softplus_f(ev.y + bfhi(xv.x));
                acc.z += softplus_f(ev.z + bflo(xv.y));
                acc.w += softplus_f(ev.w + bfhi(xv.y));
            }
        }
    }
    acc.x += __shfl(acc.x, l + 32);
    acc.y += __shfl(acc.y, l + 32);
    acc.z += __shfl(acc.z, l + 32);
    acc.w += __shfl(acc.w, l + 32);
    if (h == 0) {
        uint2 xn = *(const uint2*)(xb + (size_t)n * HID + l * 4);
        acc.x += bflo(xn.x); acc.y += bfhi(xn.x);
        acc.z += bflo(xn.y); acc.w += bfhi(xn.y);
        unsigned o0 = (unsigned)f2bf(acc.x) | ((unsigned)f2bf(acc.y) << 16);
        unsigned o1 = (unsigned)f2bf(acc.z) | ((unsigned)f2bf(acc.w) << 16);
        *(uint2*)(outb + (size_t)n * HID + l * 4) = make_uint2(o0, o1);
    }
}

// ---- pack W[n][k] (f32) into MFMA B-frag layout (bf16) ----
__global__ void pack_w(const float* __restrict__ W1, const float* __restrict__ W2,
                       unsigned short* __restrict__ pw) {
    int t = blockIdx.x * 256 + threadIdx.x;
    if (t >= 6 * 32 * 64) return;
    int lane = t & 63;
    int tile = (t >> 6) & 31;
    int mat = t >> 11;                       // 0..5 = layer*2 + which
    int kt = tile >> 3, nt = tile & 7;
    const float* W = (mat & 1) ? W2 : W1;
    W += (size_t)(mat >> 1) * HID * HID;
    int n = nt * 16 + (lane & 15);
    int kbase = kt * 32 + (lane >> 4) * 8;
    short8 v;
    #pragma unroll
    for (int j = 0; j < 8; j++) v[j] = (short)f2bf(W[(size_t)n * HID + kbase + j]);
    *((short8*)(pw + (size_t)t * 8)) = v;
}

// ---- fused MLP: out = [softplus]( softplus(A@W1^T+b1) @ W2^T + b2 ) ----
// block = 4 waves: 2 row-tiles x 2 col-halves; h round-trips via LDS (bf16).
__global__ void __launch_bounds__(256) mlp_fused(const unsigned short* __restrict__ A,
        const unsigned short* __restrict__ pw1, const unsigned short* __restrict__ pw2,
        const float* __restrict__ b1, const float* __restrict__ b2,
        void* __restrict__ outp, int final_layer) {
    __shared__ __align__(16) unsigned short hl[2][16][LDSP];
    int wave = threadIdx.x >> 6, lane = threadIdx.x & 63;
    int rt = wave >> 1, ch = wave & 1;
    int m = lane & 15, q = lane >> 4;
    int r0 = blockIdx.x * 32 + rt * 16;
    int row = r0 + m;
    bool rv = row < N_NODES;
    short8 zf = {0, 0, 0, 0, 0, 0, 0, 0};
    floatx4 zero = {0.f, 0.f, 0.f, 0.f};
    floatx4 acc[4];
    #pragma unroll
    for (int t = 0; t < 4; t++) acc[t] = zero;
    const short8* ar = (const short8*)(A + (size_t)row * HID + q * 8);
    const short8* w1 = (const short8*)pw1;
    #pragma unroll
    for (int kt = 0; kt < 4; kt++) {
        short8 af = rv ? ar[kt * 4] : zf;   // A[row][kt*32+q*8 ..+8], direct bf16
        const short8* wp = w1 + (size_t)(kt * 8 + ch * 4) * 64 + lane;
        #pragma unroll
        for (int t = 0; t < 4; t++)
            acc[t] = __builtin_amdgcn_mfma_f32_16x16x32_bf16(af, wp[t * 64], acc[t], 0, 0, 0);
    }
    // epilogue 1: h = softplus(acc + b1) -> bf16 -> LDS (C-layout -> A-layout)
    #pragma unroll
    for (int t = 0; t < 4; t++) {
        int col = ch * 64 + t * 16 + m;
        float bb = b1[col];
        #pragma unroll
        for (int i = 0; i < 4; i++)
            hl[rt][q * 4 + i][col] = f2bf(softplus_f(acc[t][i] + bb));
    }
    __syncthreads();
    #pragma unroll
    for (int t = 0; t < 4; t++) acc[t] = zero;
    const short8* w2 = (const short8*)pw2;
    #pragma unroll
    for (int kt = 0; kt < 4; kt++) {
        short8 af = *(const short8*)&hl[rt][m][kt * 32 + q * 8];
        const short8* wp = w2 + (size_t)(kt * 8 + ch * 4) * 64 + lane;
        #pragma unroll
        for (int t = 0; t < 4; t++)
            acc[t] = __builtin_amdgcn_mfma_f32_16x16x32_bf16(af, wp[t * 64], acc[t], 0, 0, 0);
    }
    if (final_layer) {
        float* out = (float*)outp;
        #pragma unroll
        for (int t = 0; t < 4; t++) {
            int col = ch * 64 + t * 16 + m;
            float bb = b2[col];
            #pragma unroll
            for (int i = 0; i < 4; i++) {
                int r = r0 + q * 4 + i;
                if (r < N_NODES) out[(size_t)r * HID + col] = acc[t][i] + bb;
            }
        }
    } else {
        __syncthreads();    // all GEMM2 LDS reads done before overwrite
        #pragma unroll
        for (int t = 0; t < 4; t++) {
            int col = ch * 64 + t * 16 + m;
            float bb = b2[col];
            #pragma unroll
            for (int i = 0; i < 4; i++)
                hl[rt][q * 4 + i][col] = f2bf(softplus_f(acc[t][i] + bb));
        }
        __syncthreads();
        // coalesced copy-out: thread -> (row = tid>>3, 16-col segment)
        unsigned short* outb = (unsigned short*)outp;
        int tid = threadIdx.x;
        int orow = tid >> 3, cseg = (tid & 7) * 16;
        int gr = blockIdx.x * 32 + orow;
        if (gr < N_NODES) {
            uint4 v0 = *(const uint4*)&hl[orow >> 4][orow & 15][cseg];
            uint4 v1 = *(const uint4*)&hl[orow >> 4][orow & 15][cseg + 8];
            *(uint4*)(outb + (size_t)gr * HID + cseg) = v0;
            *(uint4*)(outb + (size_t)gr * HID + cseg + 8) = v1;
        }
    }
}

// ---- pool: sorted batch -> boundaries -> chunked partials -> reduce ----
__global__ void find_bounds(const int* __restrict__ batch, int* __restrict__ start) {
    int n = blockIdx.x * 256 + threadIdx.x;
    if (n >= N_NODES) return;
    int bn = batch[n];
    int bp = (n == 0) ? -1 : batch[n - 1];
    for (int g = bp + 1; g <= bn; g++) start[g] = n;
    if (n == N_NODES - 1)
        for (int g = bn + 1; g <= N_GRAPHS; g++) start[g] = N_NODES;
}

__global__ void pool_partial(const float* __restrict__ nf, const int* __restrict__ start,
                             float* __restrict__ part) {
    int g = blockIdx.x >> 3, c = blockIdx.x & (PCHUNK - 1);
    int j = threadIdx.x;
    int s = start[g], e = start[g + 1];
    int len = e - s;
    int b0 = s + (len * c) / PCHUNK;
    int b1 = s + (len * (c + 1)) / PCHUNK;
    float acc = 0.f;
    for (int n = b0; n < b1; n++) acc += nf[(size_t)n * HID + j];
    part[(size_t)blockIdx.x * HID + j] = acc;
}

__global__ void pool_final(const float* __restrict__ part, float* __restrict__ gout) {
    int g = blockIdx.x, j = threadIdx.x;
    float acc = 0.f;
    #pragma unroll
    for (int c = 0; c < PCHUNK; c++) acc += part[(size_t)(g * PCHUNK + c) * HID + j];
    gout[(size_t)g * HID + j] = acc;
}

extern "C" void kernel_launch(void* const* d_in, const int* in_sizes, int n_in,
                              void* d_out, int out_size, void* d_ws, size_t ws_size,
                              hipStream_t stream) {
    const float* node_attr = (const float*)d_in[0];
    const float* edge_attr = (const float*)d_in[1];
    const int*   ei        = (const int*)d_in[2];
    const int*   batch     = (const int*)d_in[3];
    const float* W1        = (const float*)d_in[4];
    const float* B1        = (const float*)d_in[5];
    const float* W2        = (const float*)d_in[6];
    const float* B2        = (const float*)d_in[7];

    float* gout    = (float*)d_out;                    // [64,128]
    float* nodeout = (float*)d_out + N_GRAPHS * HID;   // [50000,128]

    const size_t NH = (size_t)N_NODES * HID;
    unsigned short* nab  = (unsigned short*)d_ws;      // bf16 node_attr
    unsigned short* bufA = nab + NH;                   // bf16 agg out (MLP A)
    unsigned short* bufB = bufA + NH;                  // bf16 x between layers
    unsigned short* ebs  = bufB + NH;                  // bf16 dst-ordered CSR edge rows
    int*   cnt = (int*)(ebs + (size_t)N_EDGES * HID);  // [0..49999]=deg, [50000]=ovf cnt
    int4*  ovf = (int4*)(cnt + 50004);                 // OVF_CAP (16B aligned)
    int2*  sed = (int2*)(ovf + OVF_CAP);               // per-edge (dst,slot)
    int*   srcs = (int*)(sed + N_EDGES);               // CSR-ordered src ids
    int*   off = srcs + N_EDGES;                       // CSR base per node
    unsigned short* pw = (unsigned short*)(off + 50000);  // 6*16384 (16B aligned)
    int*   startb = (int*)(pw + 6 * 16384);            // 65 (+pad)
    float* part = (float*)(startb + 68);               // 64*PCHUNK*128

    hipMemsetAsync(cnt, 0, (size_t)50001 * sizeof(int), stream);
    build_buckets2<<<(N_EDGES + 255) / 256, 256, 0, stream>>>(ei, cnt, sed, ovf);
    scan_off<<<1, 1024, 0, stream>>>(cnt, off);
    permute_e<<<(N_EDGES + 7) / 8, 256, 0, stream>>>(edge_attr, sed, ei, off, ebs, srcs);
    pack_w<<<(6 * 32 * 64 + 255) / 256, 256, 0, stream>>>(W1, W2, pw);
    pack_x<<<((int)(NH / 4) + 255) / 256, 256, 0, stream>>>(node_attr, nab, (int)(NH / 4));
    find_bounds<<<(N_NODES + 255) / 256, 256, 0, stream>>>(batch, startb);

    const int agg_blocks = (N_NODES + 3) / 4;
    const int mlp_blocks = (N_NODES + 31) / 32;

    const unsigned short* xcur = nab;
    for (int i = 0; i < 3; i++) {
        agg_seq<<<agg_blocks, 256, 0, stream>>>(xcur, edge_attr, cnt, srcs, ovf,
                bufA, ebs, off);
        void* outp = (i == 2) ? (void*)nodeout : (void*)bufB;
        mlp_fused<<<mlp_blocks, 256, 0, stream>>>(bufA,
                pw + (size_t)(i * 2) * 16384, pw + (size_t)(i * 2 + 1) * 16384,
                B1 + (size_t)i * HID, B2 + (size_t)i * HID, outp, (i == 2) ? 1 : 0);
        xcur = bufB;
    }
    pool_partial<<<N_GRAPHS * PCHUNK, HID, 0, stream>>>(nodeout, startb, part);
    pool_final<<<N_GRAPHS, HID, 0, stream>>>(part, gout);
}